// Round 1
// baseline (807.183 us; speedup 1.0000x reference)
//
#include <hip/hip_runtime.h>

// Problem constants (fixed by setup_inputs)
#define NB 2
#define LL 4800
#define SS 4800
#define CC 256
#define H0 60
#define W0 80
#define H1 60
#define W1 80
#define THRV 0.2f
#define INVST 0.0390625f   // 1/(C * TEMP) = 1/25.6 ; exact = 5/128
#define CH 16
#define CHROWS 300         // LL / CH

// Workspace float offsets
#define OF_RM   0           // [NB*LL] row max of sim
#define OF_RS   9600        // [NB*LL] row sumexp
#define OF_CM   19200       // [NB*SS] col max of sim
#define OF_CS   28800       // [NB*SS] col sumexp
#define OF_RWM  38400       // [NB*LL] row max of conf
#define OF_CLM  48000       // [NB*SS] col max of conf
#define OF_PM   57600       // [CH*NB*SS] partial col max
#define OF_PS   (57600 + 153600)       // partial col sumexp
#define OF_PMX  (57600 + 2*153600)     // partial col conf-max
// total: 518400 floats = ~2.07 MB of d_ws

// Output float offsets (conf, mask_v, j_ids, mkpts1_c, mconf)
#define O_CONF  0
#define O_MASKV 46080000ull
#define O_JIDS  46089600ull
#define O_MKPT  46099200ull
#define O_MCONF 46118400ull

// ---------------------------------------------------------------- GEMM ------
// sim[n,l,s] = dot(A[n,l,:], B[n,s,:]) * INVST ; 64x64 tile, 4x4 micro, BK=32
__global__ __launch_bounds__(256) void gemm_sim(const float* __restrict__ A,
                                                const float* __restrict__ B,
                                                float* __restrict__ out) {
    __shared__ __align__(16) float As[32][68];
    __shared__ __align__(16) float Bs[32][68];
    const int n = blockIdx.z;
    const float* An = A + (size_t)n * LL * CC;
    const float* Bn = B + (size_t)n * SS * CC;
    float* On = out + (size_t)n * LL * SS;
    const int l0 = blockIdx.y << 6, s0 = blockIdx.x << 6;
    const int tid = threadIdx.x;
    const int tx = tid & 15, ty = tid >> 4;

    float acc[4][4] = {};

    for (int k0 = 0; k0 < CC; k0 += 32) {
#pragma unroll
        for (int i = 0; i < 2; i++) {
            const int f = tid + (i << 8);
            const int row = f >> 3;
            const int kv = (f & 7) << 2;
            const float4 a = *(const float4*)(An + (size_t)(l0 + row) * CC + k0 + kv);
            const float4 b = *(const float4*)(Bn + (size_t)(s0 + row) * CC + k0 + kv);
            As[kv + 0][row] = a.x; As[kv + 1][row] = a.y;
            As[kv + 2][row] = a.z; As[kv + 3][row] = a.w;
            Bs[kv + 0][row] = b.x; Bs[kv + 1][row] = b.y;
            Bs[kv + 2][row] = b.z; Bs[kv + 3][row] = b.w;
        }
        __syncthreads();
#pragma unroll
        for (int k = 0; k < 32; k++) {
            const float4 a = *(const float4*)&As[k][ty << 2];
            const float4 b = *(const float4*)&Bs[k][tx << 2];
            acc[0][0] += a.x * b.x; acc[0][1] += a.x * b.y; acc[0][2] += a.x * b.z; acc[0][3] += a.x * b.w;
            acc[1][0] += a.y * b.x; acc[1][1] += a.y * b.y; acc[1][2] += a.y * b.z; acc[1][3] += a.y * b.w;
            acc[2][0] += a.z * b.x; acc[2][1] += a.z * b.y; acc[2][2] += a.z * b.z; acc[2][3] += a.z * b.w;
            acc[3][0] += a.w * b.x; acc[3][1] += a.w * b.y; acc[3][2] += a.w * b.z; acc[3][3] += a.w * b.w;
        }
        __syncthreads();
    }
#pragma unroll
    for (int i = 0; i < 4; i++) {
        float4 v = make_float4(acc[i][0] * INVST, acc[i][1] * INVST,
                               acc[i][2] * INVST, acc[i][3] * INVST);
        *(float4*)(On + (size_t)(l0 + (ty << 2) + i) * SS + s0 + (tx << 2)) = v;
    }
}

// ------------------------------------------------------------ row stats -----
__global__ __launch_bounds__(256) void row_stats(const float* __restrict__ sim,
                                                 float* __restrict__ ws) {
    const int l = blockIdx.x, n = blockIdx.y;
    const float* row = sim + ((size_t)n * LL + l) * SS;
    __shared__ float red[256];
    const int tid = threadIdx.x;

    float tmax = -__builtin_inff();
    for (int s = tid; s < SS; s += 256) tmax = fmaxf(tmax, row[s]);
    red[tid] = tmax;
    __syncthreads();
    for (int off = 128; off > 0; off >>= 1) {
        if (tid < off) red[tid] = fmaxf(red[tid], red[tid + off]);
        __syncthreads();
    }
    const float M = red[0];
    __syncthreads();

    float tsum = 0.f;
    for (int s = tid; s < SS; s += 256) tsum += __expf(row[s] - M);
    red[tid] = tsum;
    __syncthreads();
    for (int off = 128; off > 0; off >>= 1) {
        if (tid < off) red[tid] += red[tid + off];
        __syncthreads();
    }
    if (tid == 0) {
        ws[OF_RM + n * LL + l] = M;
        ws[OF_RS + n * LL + l] = red[0];
    }
}

// ------------------------------------------------------------ col stats -----
__global__ __launch_bounds__(256) void col_partial(const float* __restrict__ sim,
                                                   float* __restrict__ ws) {
    const int s = blockIdx.x * 256 + threadIdx.x;
    const int n = blockIdx.y, ch = blockIdx.z;
    if (s >= SS) return;
    const float* p = sim + ((size_t)n * LL + ch * CHROWS) * SS + s;
    float m = p[0];
    float sum = 1.f;
    for (int i = 1; i < CHROWS; i++) {
        const float x = p[(size_t)i * SS];
        if (x > m) { sum = sum * __expf(m - x) + 1.f; m = x; }
        else       { sum += __expf(x - m); }
    }
    ws[OF_PM + ((size_t)ch * NB + n) * SS + s] = m;
    ws[OF_PS + ((size_t)ch * NB + n) * SS + s] = sum;
}

__global__ __launch_bounds__(256) void col_combine(float* __restrict__ ws) {
    const int s = blockIdx.x * 256 + threadIdx.x;
    const int n = blockIdx.y;
    if (s >= SS) return;
    float m = ws[OF_PM + (size_t)n * SS + s];
    float sum = ws[OF_PS + (size_t)n * SS + s];
    for (int ch = 1; ch < CH; ch++) {
        const float m2 = ws[OF_PM + ((size_t)ch * NB + n) * SS + s];
        const float s2 = ws[OF_PS + ((size_t)ch * NB + n) * SS + s];
        const float nm = fmaxf(m, m2);
        sum = sum * __expf(m - nm) + s2 * __expf(m2 - nm);
        m = nm;
    }
    ws[OF_CM + n * SS + s] = m;
    ws[OF_CS + n * SS + s] = sum;
}

// ------------------------------------------------------- conf + row max -----
__global__ __launch_bounds__(256) void conf_pass(float* __restrict__ sim,
                                                 float* __restrict__ ws) {
    const int l = blockIdx.x, n = blockIdx.y;
    const size_t base = ((size_t)n * LL + l) * SS;
    const int tid = threadIdx.x;
    const float M = ws[OF_RM + n * LL + l];
    const float Rinv = 1.0f / ws[OF_RS + n * LL + l];
    const float* cm = ws + OF_CM + (size_t)n * SS;
    const float* cs = ws + OF_CS + (size_t)n * SS;
    __shared__ float red[256];

    float tmax = 0.f;
    for (int s = tid; s < SS; s += 256) {
        const float x = sim[base + s];
        const float c = (__expf(x - M) * Rinv) * (__expf(x - cm[s]) / cs[s]);
        sim[base + s] = c;
        tmax = fmaxf(tmax, c);
    }
    red[tid] = tmax;
    __syncthreads();
    for (int off = 128; off > 0; off >>= 1) {
        if (tid < off) red[tid] = fmaxf(red[tid], red[tid + off]);
        __syncthreads();
    }
    if (tid == 0) ws[OF_RWM + n * LL + l] = red[0];
}

// --------------------------------------------------------- conf col max -----
__global__ __launch_bounds__(256) void colmax_partial(const float* __restrict__ conf,
                                                      float* __restrict__ ws) {
    const int s = blockIdx.x * 256 + threadIdx.x;
    const int n = blockIdx.y, ch = blockIdx.z;
    if (s >= SS) return;
    const float* p = conf + ((size_t)n * LL + ch * CHROWS) * SS + s;
    float m = 0.f;
    for (int i = 0; i < CHROWS; i++) m = fmaxf(m, p[(size_t)i * SS]);
    ws[OF_PMX + ((size_t)ch * NB + n) * SS + s] = m;
}

__global__ __launch_bounds__(256) void colmax_combine(float* __restrict__ ws) {
    const int s = blockIdx.x * 256 + threadIdx.x;
    const int n = blockIdx.y;
    if (s >= SS) return;
    float m = 0.f;
    for (int ch = 0; ch < CH; ch++)
        m = fmaxf(m, ws[OF_PMX + ((size_t)ch * NB + n) * SS + s]);
    ws[OF_CLM + n * SS + s] = m;
}

// ------------------------------------------------------------- matching -----
__global__ __launch_bounds__(256) void match_pass(const float* __restrict__ conf,
                                                  const float* __restrict__ ws,
                                                  float* __restrict__ out) {
    const int l = blockIdx.x, n = blockIdx.y;
    const size_t base = ((size_t)n * LL + l) * SS;
    const int tid = threadIdx.x;
    const int y0 = l / W0, x0 = l % W0;
    const bool rvalid = (y0 >= 2 && y0 < H0 - 2 && x0 >= 2 && x0 < W0 - 2);
    __shared__ int red[256];

    int best = SS;
    if (rvalid) {
        const float rwm = ws[OF_RWM + n * LL + l];
        const float* clm = ws + OF_CLM + (size_t)n * SS;
        for (int s = tid; s < SS; s += 256) {
            const float c = conf[base + s];
            if (c > THRV && c == rwm && c == clm[s]) {
                const int y1 = s / W1, x1 = s % W1;
                if (y1 >= 2 && y1 < H1 - 2 && x1 >= 2 && x1 < W1 - 2)
                    best = min(best, s);
            }
        }
    }
    red[tid] = best;
    __syncthreads();
    for (int off = 128; off > 0; off >>= 1) {
        if (tid < off) red[tid] = min(red[tid], red[tid + off]);
        __syncthreads();
    }
    if (tid == 0) {
        int j = red[0];
        const bool any = j < SS;
        if (!any) j = 0;
        out[O_MASKV + n * LL + l] = any ? 1.f : 0.f;
        out[O_JIDS + n * LL + l] = (float)j;
        out[O_MKPT + ((size_t)n * LL + l) * 2 + 0] = (float)(j % W1);
        out[O_MKPT + ((size_t)n * LL + l) * 2 + 1] = (float)(j / W1);
        out[O_MCONF + n * LL + l] = any ? conf[base + j] : 0.f;
    }
}

// -------------------------------------------------------------- launch ------
extern "C" void kernel_launch(void* const* d_in, const int* in_sizes, int n_in,
                              void* d_out, int out_size, void* d_ws, size_t ws_size,
                              hipStream_t stream) {
    const float* f0 = (const float*)d_in[0];
    const float* f1 = (const float*)d_in[1];
    float* out = (float*)d_out;
    float* ws = (float*)d_ws;

    gemm_sim<<<dim3(SS / 64, LL / 64, NB), 256, 0, stream>>>(f0, f1, out);
    row_stats<<<dim3(LL, NB), 256, 0, stream>>>(out, ws);
    col_partial<<<dim3((SS + 255) / 256, NB, CH), 256, 0, stream>>>(out, ws);
    col_combine<<<dim3((SS + 255) / 256, NB), 256, 0, stream>>>(ws);
    conf_pass<<<dim3(LL, NB), 256, 0, stream>>>(out, ws);
    colmax_partial<<<dim3((SS + 255) / 256, NB, CH), 256, 0, stream>>>(out, ws);
    colmax_combine<<<dim3((SS + 255) / 256, NB), 256, 0, stream>>>(ws);
    match_pass<<<dim3(LL, NB), 256, 0, stream>>>(out, ws, out);
}

// Round 2
// 326.051 us; speedup vs baseline: 2.4756x; 2.4756x over previous
//
#include <hip/hip_runtime.h>

typedef _Float16 half8 __attribute__((ext_vector_type(8)));
typedef float f32x4 __attribute__((ext_vector_type(4)));

#define NB 2
#define LS 4800
#define CCH 256
#define W0 80
#define W1 80
#define THRV 0.2f
#define SQS 0.19764235376052370f   // sqrt(1/(C*TEMP)) = sqrt(1/25.6)

#define TN 38          // tiles per dim -> padded 4864
#define PADL 4864

// ---- ws float offsets (total ~16.02 MB needed) ----
#define OF_RM   0           // [NB*LS] sim row max
#define OF_RSI  9600        // [NB*LS] 1/row sumexp
#define OF_CM   19200       // [NB*LS] sim col max
#define OF_CSI  28800       // [NB*LS] 1/col sumexp
#define OF_RWM  38400       // [NB*LS] conf row max
#define OF_CAND 48000       // [NB*LS] (int) argmax col of conf row max
#define OF_CLM  57600       // [NB*LS] conf col max (int-as-float via atomicMax)
#define OF_PROW 67200                   // float2 [NB][TN][PADL] row partials (m,s)
#define OF_PCOL (67200 + 739328)        // float2 [NB][TN][PADL] col partials
#define OF_AH   (67200 + 2*739328)      // _Float16 [NB][LS][CCH]
#define OF_BH   (OF_AH + 1228800)

// ---- out float offsets (conf, mask_v, j_ids, mkpts1_c, mconf) ----
#define O_MASKV 46080000ull
#define O_JIDS  46089600ull
#define O_MKPT  46099200ull
#define O_MCONF 46118400ull

__device__ __forceinline__ void load_lds16(const void* g, void* l) {
    __builtin_amdgcn_global_load_lds((const __attribute__((address_space(1))) void*)g,
                                     (__attribute__((address_space(3))) void*)l, 16, 0, 0);
}

// --------------------------------------------------------- f32 -> f16 cast --
__global__ __launch_bounds__(256) void conv_half(const float* __restrict__ A,
                                                 const float* __restrict__ B,
                                                 float* __restrict__ ws) {
    const int which = blockIdx.y;
    const float* src = which ? B : A;
    _Float16* dst = (_Float16*)(ws + (which ? OF_BH : OF_AH));
    const int idx = blockIdx.x * 256 + threadIdx.x;   // float4 index, 614400 total
    const float4 v = ((const float4*)src)[idx];
    union { _Float16 h[4]; uint2 u; } p;
    p.h[0] = (_Float16)(v.x * SQS);
    p.h[1] = (_Float16)(v.y * SQS);
    p.h[2] = (_Float16)(v.z * SQS);
    p.h[3] = (_Float16)(v.w * SQS);
    ((uint2*)dst)[idx] = p.u;
}

// ---------------------------------------------- MFMA GEMM + sim stat partials
// sim = (A*sqs)(B*sqs)^T, 128x128 tile, BK=64, K=256. LDS layout per tile:
// slot(row,q) = row*8 + (q ^ (row&7)); slot holds A[row][q*8..q*8+8) f16.
// Staging (global_load_lds, lane L of chunk c): row=c*8+(L>>3), q=(L&7)^((L>>3)&7)
// -> coalesced 128B per 8 lanes AND conflict-free ds_read_b128 frag reads.
__global__ __launch_bounds__(256, 2) void gemm_mfma(float* __restrict__ out,
                                                    float* __restrict__ ws) {
    __shared__ __align__(16) union {
        struct { _Float16 A[8192]; _Float16 B[8192]; } st;       // 16KB + 16KB
        struct { float rs[128][2][2]; float cs[128][2][2]; } red; // 4KB
    } sm;
    const int bx = blockIdx.x, by = blockIdx.y, n = blockIdx.z;
    const _Float16* Ah = (const _Float16*)(ws + OF_AH) + (size_t)n * LS * CCH;
    const _Float16* Bh = (const _Float16*)(ws + OF_BH) + (size_t)n * LS * CCH;
    const int tid = threadIdx.x;
    const int lane = tid & 63, w = tid >> 6;
    const int wx = w & 1, wy = w >> 1;
    const int m = lane & 15, quad = lane >> 4;

    f32x4 acc[4][4];
    {
        f32x4 z = {0.f, 0.f, 0.f, 0.f};
#pragma unroll
        for (int a = 0; a < 4; a++)
#pragma unroll
            for (int b = 0; b < 4; b++) acc[a][b] = z;
    }

    const int srow = lane >> 3;                 // 0..7 within chunk
    const int qst = (lane & 7) ^ (srow & 7);    // swizzled k-group

    for (int kt = 0; kt < 4; kt++) {
        const int k0 = kt * 64;
#pragma unroll
        for (int i = 0; i < 4; i++) {           // A: 16 chunks of 1KB, c = i*4+w
            const int c = i * 4 + w;
            int gr = by * 128 + c * 8 + srow; gr = gr < LS ? gr : LS - 1;
            load_lds16(Ah + (size_t)gr * CCH + k0 + qst * 8, &sm.st.A[c * 512]);
        }
#pragma unroll
        for (int i = 0; i < 4; i++) {
            const int c = i * 4 + w;
            int gr = bx * 128 + c * 8 + srow; gr = gr < LS ? gr : LS - 1;
            load_lds16(Bh + (size_t)gr * CCH + k0 + qst * 8, &sm.st.B[c * 512]);
        }
        __syncthreads();
#pragma unroll
        for (int t = 0; t < 2; t++) {
            half8 Af[4], Bf[4];
#pragma unroll
            for (int a = 0; a < 4; a++) {
                const int rl = wy * 64 + a * 16 + m;
                const int sl = rl * 8 + ((t * 4 + quad) ^ (rl & 7));
                Af[a] = *(const half8*)&sm.st.A[sl * 8];
            }
#pragma unroll
            for (int b = 0; b < 4; b++) {
                const int cl = wx * 64 + b * 16 + m;
                const int sl = cl * 8 + ((t * 4 + quad) ^ (cl & 7));
                Bf[b] = *(const half8*)&sm.st.B[sl * 8];
            }
#pragma unroll
            for (int a = 0; a < 4; a++)
#pragma unroll
                for (int b = 0; b < 4; b++)
                    acc[a][b] = __builtin_amdgcn_mfma_f32_16x16x32_f16(Af[a], Bf[b], acc[a][b], 0, 0, 0);
        }
        __syncthreads();
    }

    // ---- store sim (C/D layout: row = quad*4+reg, col = m) ----
    const int l0 = by * 128, s0 = bx * 128;
    float* On = out + (size_t)n * LS * LS;
#pragma unroll
    for (int a = 0; a < 4; a++) {
        const int gr0 = l0 + wy * 64 + a * 16 + quad * 4;
#pragma unroll
        for (int reg = 0; reg < 4; reg++) {
            const int gr = gr0 + reg;
            if (gr < LS) {
#pragma unroll
                for (int b = 0; b < 4; b++) {
                    const int gc = s0 + wx * 64 + b * 16 + m;
                    if (gc < LS) On[(size_t)gr * LS + gc] = acc[a][b][reg];
                }
            }
        }
    }

    // ---- fused per-tile softmax partials ----
    bool bval[4];
#pragma unroll
    for (int b = 0; b < 4; b++) bval[b] = (s0 + wx * 64 + b * 16 + m) < LS;
    bool aval[4][4];
#pragma unroll
    for (int a = 0; a < 4; a++)
#pragma unroll
        for (int reg = 0; reg < 4; reg++)
            aval[a][reg] = (l0 + wy * 64 + a * 16 + quad * 4 + reg) < LS;

    // row stats: per (a,reg) reduce over b and 16 lanes (m)
#pragma unroll
    for (int a = 0; a < 4; a++) {
#pragma unroll
        for (int reg = 0; reg < 4; reg++) {
            float mx = -1e30f;
#pragma unroll
            for (int b = 0; b < 4; b++) if (bval[b]) mx = fmaxf(mx, acc[a][b][reg]);
            for (int d = 1; d < 16; d <<= 1) mx = fmaxf(mx, __shfl_xor(mx, d, 64));
            float sum = 0.f;
#pragma unroll
            for (int b = 0; b < 4; b++) if (bval[b]) sum += __expf(acc[a][b][reg] - mx);
            for (int d = 1; d < 16; d <<= 1) sum += __shfl_xor(sum, d, 64);
            if (m == 0) {
                const int rl = wy * 64 + a * 16 + quad * 4 + reg;
                sm.red.rs[rl][wx][0] = mx; sm.red.rs[rl][wx][1] = sum;
            }
        }
    }
    // col stats: per b reduce over (a,reg) and quads
#pragma unroll
    for (int b = 0; b < 4; b++) {
        float mx = -1e30f;
#pragma unroll
        for (int a = 0; a < 4; a++)
#pragma unroll
            for (int reg = 0; reg < 4; reg++)
                if (aval[a][reg]) mx = fmaxf(mx, acc[a][b][reg]);
        float sum = 0.f;
#pragma unroll
        for (int a = 0; a < 4; a++)
#pragma unroll
            for (int reg = 0; reg < 4; reg++)
                if (aval[a][reg]) sum += __expf(acc[a][b][reg] - mx);
        for (int d = 16; d < 64; d <<= 1) {
            const float mo = __shfl_xor(mx, d, 64);
            const float so = __shfl_xor(sum, d, 64);
            const float nm = fmaxf(mx, mo);
            sum = sum * __expf(mx - nm) + so * __expf(mo - nm);
            mx = nm;
        }
        if (quad == 0) {
            const int cl = wx * 64 + b * 16 + m;
            sm.red.cs[cl][wy][0] = mx; sm.red.cs[cl][wy][1] = sum;
        }
    }
    __syncthreads();
    if (tid < 128) {
        const float m0 = sm.red.rs[tid][0][0], v0 = sm.red.rs[tid][0][1];
        const float m1 = sm.red.rs[tid][1][0], v1 = sm.red.rs[tid][1][1];
        const float nm = fmaxf(m0, m1);
        const float s = v0 * __expf(m0 - nm) + v1 * __expf(m1 - nm);
        ((float2*)(ws + OF_PROW))[((size_t)n * TN + bx) * PADL + by * 128 + tid] = make_float2(nm, s);
    } else {
        const int t = tid - 128;
        const float m0 = sm.red.cs[t][0][0], v0 = sm.red.cs[t][0][1];
        const float m1 = sm.red.cs[t][1][0], v1 = sm.red.cs[t][1][1];
        const float nm = fmaxf(m0, m1);
        const float s = v0 * __expf(m0 - nm) + v1 * __expf(m1 - nm);
        ((float2*)(ws + OF_PCOL))[((size_t)n * TN + by) * PADL + bx * 128 + t] = make_float2(nm, s);
    }
}

// -------------------------------------------------- combine 38 partials -----
__global__ __launch_bounds__(256) void combine_stats(float* __restrict__ ws) {
    const int idx = blockIdx.x * 256 + threadIdx.x;   // 19200 total
    const int half_ = idx >= 9600;
    const int i = idx - half_ * 9600;
    const int n = i / LS, r = i % LS;
    const float2* P = (const float2*)(ws + (half_ ? OF_PCOL : OF_PROW)) + (size_t)n * TN * PADL + r;
    float M = -1e30f, S = 0.f;
    for (int b = 0; b < TN; b++) {
        const float2 p = P[(size_t)b * PADL];
        const float nm = fmaxf(M, p.x);
        S = S * __expf(M - nm) + p.y * __expf(p.x - nm);
        M = nm;
    }
    if (!half_) {
        ws[OF_RM + i] = M; ws[OF_RSI + i] = 1.0f / S;
        ws[OF_CLM + i] = 0.0f;   // init for atomicMax in conf_pass
    } else {
        ws[OF_CM + i] = M; ws[OF_CSI + i] = 1.0f / S;
    }
}

// ----------------- sim -> conf in place + rowmax/cand + colmax(atomic) ------
__global__ __launch_bounds__(256) void conf_pass(float* __restrict__ conf,
                                                 float* __restrict__ ws) {
    const int chunk = blockIdx.x, n = blockIdx.y;
    const int tid = threadIdx.x;
    const int r0 = chunk * 16;
    __shared__ float Lv[16][256];
    __shared__ int Li[16][256];
    __shared__ float Mv[16][16];
    __shared__ int Mi[16][16];
    float cmv[19], csiv[19], cmax[19];
#pragma unroll
    for (int j = 0; j < 19; j++) {
        const int s = tid + j * 256;
        cmax[j] = 0.f;
        if (s < LS) { cmv[j] = ws[OF_CM + n * LS + s]; csiv[j] = ws[OF_CSI + n * LS + s]; }
        else { cmv[j] = 0.f; csiv[j] = 0.f; }
    }
    for (int r = 0; r < 16; r++) {
        const int gr = r0 + r;
        const float rm = ws[OF_RM + n * LS + gr];
        const float rsi = ws[OF_RSI + n * LS + gr];
        float* row = conf + ((size_t)n * LS + gr) * LS;
        float lmax = -1.f; int lidx = 0;
#pragma unroll
        for (int j = 0; j < 19; j++) {
            const int s = tid + j * 256;
            if (s < LS) {
                const float x = row[s];
                const float c = __expf(2.f * x - rm - cmv[j]) * (rsi * csiv[j]);
                row[s] = c;
                cmax[j] = fmaxf(cmax[j], c);
                if (c > lmax) { lmax = c; lidx = s; }
            }
        }
        Lv[r][tid] = lmax; Li[r][tid] = lidx;
    }
    __syncthreads();
    {
        const int r = tid >> 4, p = tid & 15;
        float bv = -2.f; int bi = 0;
        for (int k = 0; k < 16; k++) {
            const float v = Lv[r][p * 16 + k]; const int ii = Li[r][p * 16 + k];
            if (v > bv || (v == bv && ii < bi)) { bv = v; bi = ii; }
        }
        Mv[r][p] = bv; Mi[r][p] = bi;
    }
    __syncthreads();
    if (tid < 16) {
        float bv = -2.f; int bi = 0;
        for (int p = 0; p < 16; p++) {
            const float v = Mv[tid][p]; const int ii = Mi[tid][p];
            if (v > bv || (v == bv && ii < bi)) { bv = v; bi = ii; }
        }
        ws[OF_RWM + n * LS + r0 + tid] = bv;
        ((int*)ws)[OF_CAND + n * LS + r0 + tid] = bi;
    }
    int* clm = (int*)ws + OF_CLM + n * LS;
#pragma unroll
    for (int j = 0; j < 19; j++) {
        const int s = tid + j * 256;
        if (s < LS && cmax[j] > 0.f) atomicMax(&clm[s], __float_as_int(cmax[j]));
    }
}

// ------------------------------------------------------------- matching -----
__global__ __launch_bounds__(256) void match_pass(const float* __restrict__ ws,
                                                  float* __restrict__ out) {
    const int idx = blockIdx.x * 256 + threadIdx.x;
    if (idx >= NB * LS) return;
    const int n = idx / LS, l = idx % LS;
    const float rwm = ws[OF_RWM + idx];
    const int cand = ((const int*)ws)[OF_CAND + idx];
    const float clm = ws[OF_CLM + n * LS + cand];
    const int y0 = l / W0, x0 = l % W0;
    const int y1 = cand / W1, x1 = cand % W1;
    const bool b0 = (y0 >= 2 && y0 < 58 && x0 >= 2 && x0 < 78);
    const bool b1 = (y1 >= 2 && y1 < 58 && x1 >= 2 && x1 < 78);
    const bool matched = (rwm > THRV) && b0 && b1 && (rwm == clm);
    const int j = matched ? cand : 0;
    out[O_MASKV + idx] = matched ? 1.f : 0.f;
    out[O_JIDS + idx] = (float)j;
    out[O_MKPT + (size_t)idx * 2 + 0] = (float)(j % W1);
    out[O_MKPT + (size_t)idx * 2 + 1] = (float)(j / W1);
    out[O_MCONF + idx] = matched ? rwm : 0.f;
}

// -------------------------------------------------------------- launch ------
extern "C" void kernel_launch(void* const* d_in, const int* in_sizes, int n_in,
                              void* d_out, int out_size, void* d_ws, size_t ws_size,
                              hipStream_t stream) {
    const float* f0 = (const float*)d_in[0];
    const float* f1 = (const float*)d_in[1];
    float* out = (float*)d_out;
    float* ws = (float*)d_ws;

    conv_half<<<dim3(2400, 2), 256, 0, stream>>>(f0, f1, ws);
    gemm_mfma<<<dim3(TN, TN, NB), 256, 0, stream>>>(out, ws);
    combine_stats<<<75, 256, 0, stream>>>(ws);
    conf_pass<<<dim3(300, NB), 256, 0, stream>>>(out, ws);
    match_pass<<<38, 256, 0, stream>>>(ws, out);
}